// Round 1
// 322.904 us; speedup vs baseline: 1.0976x; 1.0976x over previous
//
#include <hip/hip_runtime.h>

// ---------- bf16 helpers (raw ushort bit ops, RNE store) ----------
__device__ __forceinline__ float bf2f(unsigned short u) {
  union { unsigned int i; float f; } c; c.i = ((unsigned int)u) << 16; return c.f;
}
__device__ __forceinline__ unsigned short f2bf(float f) {
  union { float f; unsigned int i; } c; c.f = f;
  unsigned int x = c.i;
  return (unsigned short)((x + 0x7fffu + ((x >> 16) & 1u)) >> 16);
}
__device__ __forceinline__ float lo16(unsigned int w) { return bf2f((unsigned short)(w & 0xffffu)); }
__device__ __forceinline__ float hi16(unsigned int w) { return bf2f((unsigned short)(w >> 16)); }

#define DD 128
#define HH 64
#define CC 40
#define NBUCK 64
#define NCHUNK 256        // edge chunks (hist/scatter blocks)
#define MAXNPB 2048       // max nodes per bucket (N <= 131072)

using bf16x8 = __attribute__((ext_vector_type(8))) short;   // 8 bf16 (4 VGPRs)
using f32x4  = __attribute__((ext_vector_type(4))) float;   // 4 fp32 acc

// ---------- dtype detect ----------
__global__ void detect(const unsigned int* e32, const unsigned int* x32, int* flags) {
  __shared__ unsigned int redOr[256];
  __shared__ int redCnt[256];
  int tid = threadIdx.x;
  unsigned int v = 0;
  for (int i = tid; i < 4096; i += 256) v |= e32[2 * i + 1];
  int cnt = 0;
  for (int i = tid; i < 4096; i += 256) {
    unsigned int w = x32[i];
    unsigned int expo = (w >> 7) & 0xffu;
    unsigned short lo = (unsigned short)(w & 0xffffu);
    if (lo == 0 || (expo >= 100u && expo <= 133u)) cnt++;
  }
  redOr[tid] = v; redCnt[tid] = cnt; __syncthreads();
  for (int s = 128; s > 0; s >>= 1) {
    if (tid < s) { redOr[tid] |= redOr[tid + s]; redCnt[tid] += redCnt[tid + s]; }
    __syncthreads();
  }
  if (tid == 0) {
    flags[0] = (redOr[0] == 0u) ? 1 : 0;
    flags[1] = (redCnt[0] < 2048) ? 1 : 0;
  }
}

// ---------- radix pass 1: per-chunk 64-bin histogram ----------
__global__ __launch_bounds__(256) void hist_k(const int* e32, int E, int N,
                                              const int* flags, int nodesPerB,
                                              int* histG) {
  __shared__ int cnt[NBUCK];
  int tid = threadIdx.x;
  if (tid < NBUCK) cnt[tid] = 0;
  __syncthreads();
  int isI64 = flags[0];
  int chunk = (E + NCHUNK - 1) / NCHUNK;
  int e0 = blockIdx.x * chunk, e1 = min(e0 + chunk, E);
  for (int i = e0 + tid; i < e1; i += 256) {
    int d = isI64 ? e32[2 * (E + i)] : e32[E + i];
    d = min(max(d, 0), N - 1);
    atomicAdd(&cnt[d / nodesPerB], 1);
  }
  __syncthreads();
  if (tid < NBUCK) histG[tid * NCHUNK + blockIdx.x] = cnt[tid];
}

// ---------- radix scan (+ prep_w on block 1) ----------
// Exclusive scan of histG[16384] in (bucket,chunk) order -> ohist; bucket starts -> bbase.
// prep_w: build bf16 B-transposed weight tables for the MFMA GEMMs.
//   Wb1[n][k], n in [0,128): n<64 -> W1_l[k][n] (t path), n>=64 -> W1_r[k][n-64] (s path)
//   Wb2[n][k], n in [0,48):  n<40: k<64 -> W2_l[k][n], k>=64 -> W2_r[k-64][n]; else 0
__global__ void hscan_prepw(const int* histG, int* ohist, int* bbase, int* row_ptr,
                            int N, int E,
                            const void* W1l, const void* W1r, const void* b1,
                            const void* W2l, const void* W2r, const void* b2,
                            const int* flags, unsigned short* Wb1, unsigned short* Wb2,
                            float* b1f, float* b2f) {
  int tid = threadIdx.x;
  if (blockIdx.x == 1) {                       // prep_w role
    int isf = flags[1];
    auto rd = [&](const void* p, int i) -> float {
      return isf ? ((const float*)p)[i] : bf2f(((const unsigned short*)p)[i]);
    };
    for (int idx = tid; idx < 128 * 128; idx += 1024) {
      int n = idx >> 7, k = idx & 127;
      float v = (n < HH) ? rd(W1l, k * HH + n) : rd(W1r, k * HH + (n - HH));
      Wb1[idx] = f2bf(v);
    }
    for (int idx = tid; idx < 48 * 128; idx += 1024) {
      int n = idx >> 7, k = idx & 127;
      float v = 0.f;
      if (n < CC) v = (k < HH) ? rd(W2l, k * CC + n) : rd(W2r, (k - HH) * CC + n);
      Wb2[idx] = f2bf(v);
    }
    if (tid < HH) b1f[tid] = rd(b1, tid);
    if (tid < CC) b2f[tid] = rd(b2, tid);
    return;
  }
  __shared__ int tmp[1024];
  int v[16];
  int base = tid * 16;
  int s = 0;
#pragma unroll
  for (int k = 0; k < 16; k++) { v[k] = histG[base + k]; s += v[k]; }
  tmp[tid] = s; __syncthreads();
  for (int st = 1; st < 1024; st <<= 1) {
    int t = (tid >= st) ? tmp[tid - st] : 0;
    __syncthreads();
    tmp[tid] += t;
    __syncthreads();
  }
  int run = tmp[tid] - s;                      // exclusive prefix
#pragma unroll
  for (int k = 0; k < 16; k++) { ohist[base + k] = run; run += v[k]; }
  __syncthreads();
  if (tid < NBUCK) bbase[tid] = ohist[tid * NCHUNK];
  if (tid == 0) { bbase[NBUCK] = E; row_ptr[N] = E; }
}

// ---------- radix pass 2: scatter edges to bucket-contiguous ebuf ----------
__global__ __launch_bounds__(256) void scatter_k(const int* e32, int E, int N,
                                                 const int* flags, int nodesPerB,
                                                 const int* ohist, uint2* ebuf) {
  __shared__ int cur[NBUCK];
  int tid = threadIdx.x;
  if (tid < NBUCK) cur[tid] = ohist[tid * NCHUNK + blockIdx.x];
  __syncthreads();
  int isI64 = flags[0];
  int chunk = (E + NCHUNK - 1) / NCHUNK;
  int e0 = blockIdx.x * chunk, e1 = min(e0 + chunk, E);
  for (int i = e0 + tid; i < e1; i += 256) {
    int s, d;
    if (isI64) { s = e32[2 * i]; d = e32[2 * (E + i)]; }
    else       { s = e32[i];     d = e32[E + i]; }
    s = min(max(s, 0), N - 1);
    d = min(max(d, 0), N - 1);
    int p = atomicAdd(&cur[d / nodesPerB], 1);
    ebuf[p] = make_uint2((unsigned)s, (unsigned)d);
  }
}

// ---------- hybrid: bucketB (CSR finalize, L2-local) ∥ transform1 (MFMA GEMM) ----------
// transform1: per block 64 nodes, 4 waves x 16 nodes. t1 = x@W1_l (bf16), s1 = x@W1_r + b1.
// mfma_f32_16x16x32_bf16 frag layout: A row = lane&15, k = 8*(lane>>4)+j (contig 8);
// B col = lane&15, same k; D col = lane&15, row = (lane>>4)*4 + reg.
__global__ __launch_bounds__(256) void bktB_or_t1(
    const uint2* ebuf, const int* bbase,
    int nbuck, int nodesPerB, int* row_ptr, float* invd, int* col, int N,
    const void* xraw, const int* flags, const unsigned short* Wb1, const float* b1f,
    unsigned short* t1, unsigned short* s1, int T1B) {
  __shared__ int ldsb[MAXNPB + 256];           // 9.2 KB, bucketB role only
  int b = blockIdx.x;
  int tid = threadIdx.x;

  if (b < nbuck) {                             // ---- bucketB role ----
    int* cnt = ldsb;                           // [MAXNPB]
    int* sA  = ldsb + MAXNPB;                  // [256]
    int base_node = b * nodesPerB;
    int nn = min(nodesPerB, N - base_node);
    if (nn <= 0) return;
    int eb0 = bbase[b], eb1 = bbase[b + 1];
    int nE = eb1 - eb0;
    const uint2* ee = ebuf + eb0;
    for (int i = tid; i < nn; i += 256) cnt[i] = 0;
    __syncthreads();
    for (int i = tid; i < nE; i += 256)
      atomicAdd(&cnt[(int)ee[i].y - base_node], 1);
    __syncthreads();
    int per = (nn + 255) / 256;                // <= 8
    int myb = tid * per;
    int dreg[8];
    int ssum = 0;
#pragma unroll
    for (int k = 0; k < 8; k++) {
      int idx = myb + k;
      int v = (k < per && idx < nn) ? cnt[idx] : 0;
      dreg[k] = v; ssum += v;
    }
    sA[tid] = ssum;
    __syncthreads();
    for (int st = 1; st < 256; st <<= 1) {
      int t = (tid >= st) ? sA[tid - st] : 0;
      __syncthreads();
      sA[tid] += t;
      __syncthreads();
    }
    int run = eb0 + sA[tid] - ssum;
    __syncthreads();
#pragma unroll
    for (int k = 0; k < 8; k++) {
      int idx = myb + k;
      if (k < per && idx < nn) {
        row_ptr[base_node + idx] = run;
        invd[base_node + idx] = 1.0f / (float)max(dreg[k], 1);
        cnt[idx] = run;                        // absolute fill cursor
        run += dreg[k];
      }
    }
    __syncthreads();
    for (int i = tid; i < nE; i += 256) {
      uint2 eg = ee[i];
      int p = atomicAdd(&cnt[(int)eg.y - base_node], 1);
      col[p] = (int)eg.x;
    }
    return;
  }

  // ---- transform1 role (MFMA) ----
  int t = b - nbuck;
  if (t >= T1B) return;
  int lane = tid & 63, wv = tid >> 6;
  int nb = t * 64 + wv * 16;                   // wave's first node
  int oc = lane & 15, kgrp = lane >> 4;
  int node = min(nb + oc, N - 1);              // A-row node (clamped; tail stores guarded)
  f32x4 acc[8];
#pragma unroll
  for (int i = 0; i < 8; i++) acc[i] = (f32x4){0.f, 0.f, 0.f, 0.f};

  if (flags[1]) {                              // fp32 input: load + cvt to bf16 frag
    const float4* x4 = (const float4*)xraw;
#pragma unroll
    for (int kb = 0; kb < 4; kb++) {
      int k0 = kb * 32 + kgrp * 8;
      float4 a0 = x4[(size_t)node * 32 + (k0 >> 2)];
      float4 a1 = x4[(size_t)node * 32 + (k0 >> 2) + 1];
      bf16x8 af;
      af[0] = (short)f2bf(a0.x); af[1] = (short)f2bf(a0.y);
      af[2] = (short)f2bf(a0.z); af[3] = (short)f2bf(a0.w);
      af[4] = (short)f2bf(a1.x); af[5] = (short)f2bf(a1.y);
      af[6] = (short)f2bf(a1.z); af[7] = (short)f2bf(a1.w);
#pragma unroll
      for (int nblk = 0; nblk < 8; nblk++) {
        bf16x8 bfr = *(const bf16x8*)&Wb1[(nblk * 16 + oc) * 128 + k0];
        acc[nblk] = __builtin_amdgcn_mfma_f32_16x16x32_bf16(af, bfr, acc[nblk], 0, 0, 0);
      }
    }
  } else {                                     // bf16 input: raw 16B frag loads
    const unsigned short* x16 = (const unsigned short*)xraw;
#pragma unroll
    for (int kb = 0; kb < 4; kb++) {
      int k0 = kb * 32 + kgrp * 8;
      bf16x8 af = *(const bf16x8*)&x16[(size_t)node * 128 + k0];
#pragma unroll
      for (int nblk = 0; nblk < 8; nblk++) {
        bf16x8 bfr = *(const bf16x8*)&Wb1[(nblk * 16 + oc) * 128 + k0];
        acc[nblk] = __builtin_amdgcn_mfma_f32_16x16x32_bf16(af, bfr, acc[nblk], 0, 0, 0);
      }
    }
  }

  int r0 = kgrp * 4;                           // D rows this lane holds
#pragma unroll
  for (int nblk = 0; nblk < 8; nblk++) {
    float bias = (nblk >= 4) ? b1f[(nblk - 4) * 16 + oc] : 0.f;
#pragma unroll
    for (int r = 0; r < 4; r++) {
      int nn = nb + r0 + r;
      if (nn < N) {
        if (nblk < 4)
          t1[(size_t)nn * HH + nblk * 16 + oc] = f2bf(acc[nblk][r]);
        else
          s1[(size_t)nn * HH + (nblk - 4) * 16 + oc] = f2bf(acc[nblk][r] + bias);
      }
    }
  }
}

// ---------- vectorized CSR mean-gather (128B rows) ----------
__device__ __forceinline__ void gather_rows(const uint4* t8, const int* col,
                                            int start, int end, int r, int c,
                                            float acc[8]) {
  for (int base = start; base < end; base += 16) {
    int i0 = base + r, i1 = base + 8 + r;
    uint4 v0 = make_uint4(0, 0, 0, 0), v1 = make_uint4(0, 0, 0, 0);
    bool g0 = (i0 < end), g1 = (i1 < end);
    int nb0 = g0 ? col[i0] : 0;
    int nb1 = g1 ? col[i1] : 0;
    if (g0) v0 = t8[nb0 * 8 + c];
    if (g1) v1 = t8[nb1 * 8 + c];
    acc[0] += lo16(v0.x) + lo16(v1.x);
    acc[1] += hi16(v0.x) + hi16(v1.x);
    acc[2] += lo16(v0.y) + lo16(v1.y);
    acc[3] += hi16(v0.y) + hi16(v1.y);
    acc[4] += lo16(v0.z) + lo16(v1.z);
    acc[5] += hi16(v0.z) + hi16(v1.z);
    acc[6] += lo16(v0.w) + lo16(v1.w);
    acc[7] += hi16(v0.w) + hi16(v1.w);
  }
#pragma unroll
  for (int m = 8; m <= 32; m <<= 1)
#pragma unroll
    for (int i = 0; i < 8; i++) acc[i] += __shfl_xor(acc[i], m, 64);
}

// ---------- aggregate1: h = relu(mean(t1[nbrs]) + s1) ----------
__global__ __launch_bounds__(256) void aggregate1(const unsigned short* t1,
                                                  const unsigned short* s1,
                                                  const int* row_ptr, const float* invd,
                                                  const int* col, unsigned short* h, int N) {
  int wave = threadIdx.x >> 6, lane = threadIdx.x & 63;
  int r = lane >> 3, c = lane & 7;
  int n = blockIdx.x * 4 + wave;
  if (n >= N) return;
  int start = row_ptr[n], end = row_ptr[n + 1];
  float acc[8] = {0, 0, 0, 0, 0, 0, 0, 0};
  gather_rows((const uint4*)t1, col, start, end, r, c, acc);

  if (r == 0) {
    float id = invd[n];
    uint4 sv = ((const uint4*)s1)[n * 8 + c];
    float s[8] = {lo16(sv.x), hi16(sv.x), lo16(sv.y), hi16(sv.y),
                  lo16(sv.z), hi16(sv.z), lo16(sv.w), hi16(sv.w)};
    unsigned int o[4];
#pragma unroll
    for (int i = 0; i < 4; i++) {
      float a0 = fmaxf(acc[2 * i] * id + s[2 * i], 0.f);
      float a1 = fmaxf(acc[2 * i + 1] * id + s[2 * i + 1], 0.f);
      o[i] = (unsigned int)f2bf(a0) | ((unsigned int)f2bf(a1) << 16);
    }
    ((uint4*)h)[n * 8 + c] = make_uint4(o[0], o[1], o[2], o[3]);
  }
}

// ---------- agg2: aggh = mean(h[nbrs]) ----------
__global__ __launch_bounds__(256) void agg2(const unsigned short* h,
                                            const int* row_ptr, const float* invd,
                                            const int* col, unsigned short* aggh, int N) {
  int wave = threadIdx.x >> 6, lane = threadIdx.x & 63;
  int r = lane >> 3, c = lane & 7;
  int n = blockIdx.x * 4 + wave;
  if (n >= N) return;
  int start = row_ptr[n], end = row_ptr[n + 1];
  float acc[8] = {0, 0, 0, 0, 0, 0, 0, 0};
  gather_rows((const uint4*)h, col, start, end, r, c, acc);

  if (r == 0) {
    float id = invd[n];
    unsigned int o[4];
#pragma unroll
    for (int i = 0; i < 4; i++) {
      o[i] = (unsigned int)f2bf(acc[2 * i] * id) |
             ((unsigned int)f2bf(acc[2 * i + 1] * id) << 16);
    }
    ((uint4*)aggh)[n * 8 + c] = make_uint4(o[0], o[1], o[2], o[3]);
  }
}

// ---------- final: out = log_softmax([aggh|h] @ Wcat + b2) via MFMA ----------
// Per block 64 nodes, 4 waves x 16. K=128 (aggh|h), Nout padded 40->48 (3 nblks).
__global__ __launch_bounds__(256) void final_k(const unsigned short* aggh,
                                               const unsigned short* h,
                                               const unsigned short* Wb2,
                                               const float* b2f,
                                               float* out, int N) {
  int tid = threadIdx.x;
  int lane = tid & 63, wv = tid >> 6;
  int nb = blockIdx.x * 64 + wv * 16;
  int oc = lane & 15, kgrp = lane >> 4;
  int node = min(nb + oc, N - 1);
  f32x4 acc[3];
#pragma unroll
  for (int i = 0; i < 3; i++) acc[i] = (f32x4){0.f, 0.f, 0.f, 0.f};

#pragma unroll
  for (int kb = 0; kb < 4; kb++) {
    int k0 = kb * 32 + kgrp * 8;
    const unsigned short* src = (kb < 2) ? aggh : h;   // k<64 -> aggh, k>=64 -> h
    int kk = k0 & 63;
    bf16x8 af = *(const bf16x8*)&src[(size_t)node * HH + kk];
#pragma unroll
    for (int nblk = 0; nblk < 3; nblk++) {
      bf16x8 bfr = *(const bf16x8*)&Wb2[(nblk * 16 + oc) * 128 + k0];
      acc[nblk] = __builtin_amdgcn_mfma_f32_16x16x32_bf16(af, bfr, acc[nblk], 0, 0, 0);
    }
  }

#pragma unroll
  for (int nblk = 0; nblk < 3; nblk++) {
    int cc = nblk * 16 + oc;
    float bias = (cc < CC) ? b2f[cc] : 0.f;
#pragma unroll
    for (int r = 0; r < 4; r++) acc[nblk][r] += bias;
  }

  // per-node log-softmax: node nn = nb + kgrp*4 + r; its 48 logits live in this
  // lane's 16-lane group (cols 0..15) x 3 nblks at reg r. shfl_xor off<=8 stays in group.
#pragma unroll
  for (int r = 0; r < 4; r++) {
    int nn = nb + kgrp * 4 + r;
    float m = -INFINITY;
#pragma unroll
    for (int nblk = 0; nblk < 3; nblk++)
      if (nblk * 16 + oc < CC) m = fmaxf(m, acc[nblk][r]);
    for (int off = 1; off <= 8; off <<= 1) m = fmaxf(m, __shfl_xor(m, off, 64));
    float s = 0.f;
#pragma unroll
    for (int nblk = 0; nblk < 3; nblk++)
      if (nblk * 16 + oc < CC) s += __expf(acc[nblk][r] - m);
    for (int off = 1; off <= 8; off <<= 1) s += __shfl_xor(s, off, 64);
    float lse = m + __logf(s);
    if (nn < N) {
#pragma unroll
      for (int nblk = 0; nblk < 3; nblk++) {
        int cc = nblk * 16 + oc;
        if (cc < CC) out[(size_t)nn * CC + cc] = acc[nblk][r] - lse;
      }
    }
  }
}

extern "C" void kernel_launch(void* const* d_in, const int* in_sizes, int n_in,
                              void* d_out, int out_size, void* d_ws, size_t ws_size,
                              hipStream_t stream) {
  const void* x   = d_in[0];
  const int*  e   = (const int*)d_in[1];
  const void* W1l = d_in[2];
  const void* W1r = d_in[3];
  const void* b1  = d_in[4];
  const void* W2l = d_in[5];
  const void* W2r = d_in[6];
  const void* b2  = d_in[7];
  float* out = (float*)d_out;

  const int N = in_sizes[0] / DD;            // 100000
  const int E = in_sizes[1] / 2;             // 1600000
  const int nodesPerB = (N + NBUCK - 1) / NBUCK;   // 1563
  const int nbuck = (N + nodesPerB - 1) / nodesPerB;
  const int T1B = (N + 63) / 64;             // 1563 (64 nodes per MFMA block)

  char* w = (char*)d_ws;
  size_t off = 0;
  auto carve = [&](size_t bytes) -> void* {
    void* p = (void*)(w + off);
    off += (bytes + 255) & ~(size_t)255;
    return p;
  };
  int* col     = (int*)carve((size_t)E * 4);
  int* row_ptr = (int*)carve((size_t)(N + 1) * 4);
  float* invd  = (float*)carve((size_t)N * 4);
  int* histG   = (int*)carve((size_t)NBUCK * NCHUNK * 4);
  int* ohist   = (int*)carve((size_t)NBUCK * NCHUNK * 4);
  int* bbase   = (int*)carve((NBUCK + 1) * 4);
  int* flags   = (int*)carve(8);
  unsigned short* t1   = (unsigned short*)carve((size_t)N * HH * 2);
  unsigned short* s1   = (unsigned short*)carve((size_t)N * HH * 2);
  unsigned short* h    = (unsigned short*)carve((size_t)N * HH * 2);
  unsigned short* Wb1  = (unsigned short*)carve(128 * 128 * 2);   // [n][k] bf16
  unsigned short* Wb2  = (unsigned short*)carve(48 * 128 * 2);    // [n][k] bf16
  float* b1f   = (float*)carve(HH * sizeof(float));
  float* b2f   = (float*)carve(CC * sizeof(float));
  uint2* ebuf  = (uint2*)carve((size_t)E * 8);
  unsigned short* aggh = (unsigned short*)ebuf;   // alias: ebuf dead after hybrid
  (void)ws_size; (void)n_in; (void)out_size;

  detect<<<1, 256, 0, stream>>>((const unsigned int*)e, (const unsigned int*)x, flags);
  hist_k<<<NCHUNK, 256, 0, stream>>>(e, E, N, flags, nodesPerB, histG);
  hscan_prepw<<<2, 1024, 0, stream>>>(histG, ohist, bbase, row_ptr, N, E,
                                      W1l, W1r, b1, W2l, W2r, b2,
                                      flags, Wb1, Wb2, b1f, b2f);
  scatter_k<<<NCHUNK, 256, 0, stream>>>(e, E, N, flags, nodesPerB, ohist, ebuf);
  bktB_or_t1<<<nbuck + T1B, 256, 0, stream>>>(ebuf, bbase,
                                              nbuck, nodesPerB, row_ptr, invd, col, N,
                                              x, flags, Wb1, b1f, t1, s1, T1B);
  aggregate1<<<(N + 3) / 4, 256, 0, stream>>>(t1, s1, row_ptr, invd, col, h, N);
  agg2<<<(N + 3) / 4, 256, 0, stream>>>(h, row_ptr, invd, col, aggh, N);
  final_k<<<(N + 63) / 64, 256, 0, stream>>>(aggh, h, Wb2, b2f, out, N);
}

// Round 2
// 316.370 us; speedup vs baseline: 1.1203x; 1.0207x over previous
//
#include <hip/hip_runtime.h>

// ---------- bf16 helpers (raw ushort bit ops, RNE store) ----------
__device__ __forceinline__ float bf2f(unsigned short u) {
  union { unsigned int i; float f; } c; c.i = ((unsigned int)u) << 16; return c.f;
}
__device__ __forceinline__ unsigned short f2bf(float f) {
  union { float f; unsigned int i; } c; c.f = f;
  unsigned int x = c.i;
  return (unsigned short)((x + 0x7fffu + ((x >> 16) & 1u)) >> 16);
}
__device__ __forceinline__ float lo16(unsigned int w) { return bf2f((unsigned short)(w & 0xffffu)); }
__device__ __forceinline__ float hi16(unsigned int w) { return bf2f((unsigned short)(w >> 16)); }

#define DD 128
#define HH 64
#define CC 40
#define NBUCK 256         // radix buckets (1 block per CU in finalize)
#define NCHUNK 128        // edge chunks (hist/scatter blocks)
#define MAXNPB 512        // max nodes per bucket (N <= 131072 -> <= 512)

using bf16x8 = __attribute__((ext_vector_type(8))) short;   // 8 bf16 (4 VGPRs)
using f32x4  = __attribute__((ext_vector_type(4))) float;   // 4 fp32 acc

// ---------- dtype detect ----------
__global__ void detect(const unsigned int* e32, const unsigned int* x32, int* flags) {
  __shared__ unsigned int redOr[256];
  __shared__ int redCnt[256];
  int tid = threadIdx.x;
  unsigned int v = 0;
  for (int i = tid; i < 4096; i += 256) v |= e32[2 * i + 1];
  int cnt = 0;
  for (int i = tid; i < 4096; i += 256) {
    unsigned int w = x32[i];
    unsigned int expo = (w >> 7) & 0xffu;
    unsigned short lo = (unsigned short)(w & 0xffffu);
    if (lo == 0 || (expo >= 100u && expo <= 133u)) cnt++;
  }
  redOr[tid] = v; redCnt[tid] = cnt; __syncthreads();
  for (int s = 128; s > 0; s >>= 1) {
    if (tid < s) { redOr[tid] |= redOr[tid + s]; redCnt[tid] += redCnt[tid + s]; }
    __syncthreads();
  }
  if (tid == 0) {
    flags[0] = (redOr[0] == 0u) ? 1 : 0;
    flags[1] = (redCnt[0] < 2048) ? 1 : 0;
  }
}

// ---------- radix pass 1: per-chunk NBUCK-bin histogram ----------
__global__ __launch_bounds__(256) void hist_k(const int* e32, int E, int N,
                                              const int* flags, int nodesPerB,
                                              int* histG) {
  __shared__ int cnt[NBUCK];
  int tid = threadIdx.x;
  if (tid < NBUCK) cnt[tid] = 0;
  __syncthreads();
  int isI64 = flags[0];
  int chunk = (E + NCHUNK - 1) / NCHUNK;
  int e0 = blockIdx.x * chunk, e1 = min(e0 + chunk, E);
  for (int i = e0 + tid; i < e1; i += 256) {
    int d = isI64 ? e32[2 * (E + i)] : e32[E + i];
    d = min(max(d, 0), N - 1);
    atomicAdd(&cnt[d / nodesPerB], 1);
  }
  __syncthreads();
  if (tid < NBUCK) histG[tid * NCHUNK + blockIdx.x] = cnt[tid];
}

// ---------- radix scan (+ prep_w on block 1) ----------
// Exclusive scan of histG[NBUCK*NCHUNK = 32768] in (bucket,chunk) order -> ohist;
// bucket starts -> bbase.
// prep_w: build bf16 B-transposed weight tables for the MFMA GEMMs.
//   Wb1[n][k], n in [0,128): n<64 -> W1_l[k][n] (t path), n>=64 -> W1_r[k][n-64] (s path)
//   Wb2[n][k], n in [0,48):  n<40: k<64 -> W2_l[k][n], k>=64 -> W2_r[k-64][n]; else 0
__global__ void hscan_prepw(const int* histG, int* ohist, int* bbase, int* row_ptr,
                            int N, int E,
                            const void* W1l, const void* W1r, const void* b1,
                            const void* W2l, const void* W2r, const void* b2,
                            const int* flags, unsigned short* Wb1, unsigned short* Wb2,
                            float* b1f, float* b2f) {
  int tid = threadIdx.x;
  if (blockIdx.x == 1) {                       // prep_w role
    int isf = flags[1];
    auto rd = [&](const void* p, int i) -> float {
      return isf ? ((const float*)p)[i] : bf2f(((const unsigned short*)p)[i]);
    };
    for (int idx = tid; idx < 128 * 128; idx += 1024) {
      int n = idx >> 7, k = idx & 127;
      float v = (n < HH) ? rd(W1l, k * HH + n) : rd(W1r, k * HH + (n - HH));
      Wb1[idx] = f2bf(v);
    }
    for (int idx = tid; idx < 48 * 128; idx += 1024) {
      int n = idx >> 7, k = idx & 127;
      float v = 0.f;
      if (n < CC) v = (k < HH) ? rd(W2l, k * CC + n) : rd(W2r, (k - HH) * CC + n);
      Wb2[idx] = f2bf(v);
    }
    if (tid < HH) b1f[tid] = rd(b1, tid);
    if (tid < CC) b2f[tid] = rd(b2, tid);
    return;
  }
  __shared__ int tmp[1024];
  int v[32];
  int base = tid * 32;
  int s = 0;
#pragma unroll
  for (int k = 0; k < 32; k++) { v[k] = histG[base + k]; s += v[k]; }
  tmp[tid] = s; __syncthreads();
  for (int st = 1; st < 1024; st <<= 1) {
    int t = (tid >= st) ? tmp[tid - st] : 0;
    __syncthreads();
    tmp[tid] += t;
    __syncthreads();
  }
  int run = tmp[tid] - s;                      // exclusive prefix
#pragma unroll
  for (int k = 0; k < 32; k++) { ohist[base + k] = run; run += v[k]; }
  __syncthreads();
  if (tid < NBUCK) bbase[tid] = ohist[tid * NCHUNK];
  if (tid == 0) { bbase[NBUCK] = E; row_ptr[N] = E; }
}

// ---------- radix pass 2: scatter edges to bucket-contiguous ebuf ----------
__global__ __launch_bounds__(256) void scatter_k(const int* e32, int E, int N,
                                                 const int* flags, int nodesPerB,
                                                 const int* ohist, uint2* ebuf) {
  __shared__ int cur[NBUCK];
  int tid = threadIdx.x;
  if (tid < NBUCK) cur[tid] = ohist[tid * NCHUNK + blockIdx.x];
  __syncthreads();
  int isI64 = flags[0];
  int chunk = (E + NCHUNK - 1) / NCHUNK;
  int e0 = blockIdx.x * chunk, e1 = min(e0 + chunk, E);
  for (int i = e0 + tid; i < e1; i += 256) {
    int s, d;
    if (isI64) { s = e32[2 * i]; d = e32[2 * (E + i)]; }
    else       { s = e32[i];     d = e32[E + i]; }
    s = min(max(s, 0), N - 1);
    d = min(max(d, 0), N - 1);
    int p = atomicAdd(&cur[d / nodesPerB], 1);
    ebuf[p] = make_uint2((unsigned)s, (unsigned)d);
  }
}

// ---------- hybrid: bucketB (CSR finalize, L2-local) ∥ transform1 (MFMA GEMM) ----------
// transform1: per block 64 nodes, 4 waves x 16 nodes. t1 = x@W1_l (bf16), s1 = x@W1_r + b1.
// mfma_f32_16x16x32_bf16 frag layout: A row = lane&15, k = 8*(lane>>4)+j (contig 8);
// B col = lane&15, same k; D col = lane&15, row = (lane>>4)*4 + reg.
__global__ __launch_bounds__(256) void bktB_or_t1(
    const uint2* ebuf, const int* bbase,
    int nbuck, int nodesPerB, int* row_ptr, float* invd, int* col, int N,
    const void* xraw, const int* flags, const unsigned short* Wb1, const float* b1f,
    unsigned short* t1, unsigned short* s1, int T1B) {
  __shared__ int ldsb[MAXNPB + 256];           // 3 KB, bucketB role only
  int b = blockIdx.x;
  int tid = threadIdx.x;

  if (b < nbuck) {                             // ---- bucketB role ----
    int* cnt = ldsb;                           // [MAXNPB]
    int* sA  = ldsb + MAXNPB;                  // [256]
    int base_node = b * nodesPerB;
    int nn = min(nodesPerB, N - base_node);
    if (nn <= 0) return;
    int eb0 = bbase[b], eb1 = bbase[b + 1];
    int nE = eb1 - eb0;
    const uint2* ee = ebuf + eb0;
    for (int i = tid; i < nn; i += 256) cnt[i] = 0;
    __syncthreads();
    for (int i = tid; i < nE; i += 256)
      atomicAdd(&cnt[(int)ee[i].y - base_node], 1);
    __syncthreads();
    int per = (nn + 255) / 256;                // <= 2 at MAXNPB=512
    int myb = tid * per;
    int dreg[2];
    int ssum = 0;
#pragma unroll
    for (int k = 0; k < 2; k++) {
      int idx = myb + k;
      int v = (k < per && idx < nn) ? cnt[idx] : 0;
      dreg[k] = v; ssum += v;
    }
    sA[tid] = ssum;
    __syncthreads();
    for (int st = 1; st < 256; st <<= 1) {
      int t = (tid >= st) ? sA[tid - st] : 0;
      __syncthreads();
      sA[tid] += t;
      __syncthreads();
    }
    int run = eb0 + sA[tid] - ssum;
    __syncthreads();
#pragma unroll
    for (int k = 0; k < 2; k++) {
      int idx = myb + k;
      if (k < per && idx < nn) {
        row_ptr[base_node + idx] = run;
        invd[base_node + idx] = 1.0f / (float)max(dreg[k], 1);
        cnt[idx] = run;                        // absolute fill cursor
        run += dreg[k];
      }
    }
    __syncthreads();
    for (int i = tid; i < nE; i += 256) {
      uint2 eg = ee[i];
      int p = atomicAdd(&cnt[(int)eg.y - base_node], 1);
      col[p] = (int)eg.x;
    }
    return;
  }

  // ---- transform1 role (MFMA) ----
  int t = b - nbuck;
  if (t >= T1B) return;
  int lane = tid & 63, wv = tid >> 6;
  int nb = t * 64 + wv * 16;                   // wave's first node
  int oc = lane & 15, kgrp = lane >> 4;
  int node = min(nb + oc, N - 1);              // A-row node (clamped; tail stores guarded)
  f32x4 acc[8];
#pragma unroll
  for (int i = 0; i < 8; i++) acc[i] = (f32x4){0.f, 0.f, 0.f, 0.f};

  if (flags[1]) {                              // fp32 input: load + cvt to bf16 frag
    const float4* x4 = (const float4*)xraw;
#pragma unroll
    for (int kb = 0; kb < 4; kb++) {
      int k0 = kb * 32 + kgrp * 8;
      float4 a0 = x4[(size_t)node * 32 + (k0 >> 2)];
      float4 a1 = x4[(size_t)node * 32 + (k0 >> 2) + 1];
      bf16x8 af;
      af[0] = (short)f2bf(a0.x); af[1] = (short)f2bf(a0.y);
      af[2] = (short)f2bf(a0.z); af[3] = (short)f2bf(a0.w);
      af[4] = (short)f2bf(a1.x); af[5] = (short)f2bf(a1.y);
      af[6] = (short)f2bf(a1.z); af[7] = (short)f2bf(a1.w);
#pragma unroll
      for (int nblk = 0; nblk < 8; nblk++) {
        bf16x8 bfr = *(const bf16x8*)&Wb1[(nblk * 16 + oc) * 128 + k0];
        acc[nblk] = __builtin_amdgcn_mfma_f32_16x16x32_bf16(af, bfr, acc[nblk], 0, 0, 0);
      }
    }
  } else {                                     // bf16 input: raw 16B frag loads
    const unsigned short* x16 = (const unsigned short*)xraw;
#pragma unroll
    for (int kb = 0; kb < 4; kb++) {
      int k0 = kb * 32 + kgrp * 8;
      bf16x8 af = *(const bf16x8*)&x16[(size_t)node * 128 + k0];
#pragma unroll
      for (int nblk = 0; nblk < 8; nblk++) {
        bf16x8 bfr = *(const bf16x8*)&Wb1[(nblk * 16 + oc) * 128 + k0];
        acc[nblk] = __builtin_amdgcn_mfma_f32_16x16x32_bf16(af, bfr, acc[nblk], 0, 0, 0);
      }
    }
  }

  int r0 = kgrp * 4;                           // D rows this lane holds
#pragma unroll
  for (int nblk = 0; nblk < 8; nblk++) {
    float bias = (nblk >= 4) ? b1f[(nblk - 4) * 16 + oc] : 0.f;
#pragma unroll
    for (int r = 0; r < 4; r++) {
      int nn = nb + r0 + r;
      if (nn < N) {
        if (nblk < 4)
          t1[(size_t)nn * HH + nblk * 16 + oc] = f2bf(acc[nblk][r]);
        else
          s1[(size_t)nn * HH + (nblk - 4) * 16 + oc] = f2bf(acc[nblk][r] + bias);
      }
    }
  }
}

// ---------- vectorized CSR mean-gather (128B rows) ----------
__device__ __forceinline__ void gather_rows(const uint4* t8, const int* col,
                                            int start, int end, int r, int c,
                                            float acc[8]) {
  for (int base = start; base < end; base += 16) {
    int i0 = base + r, i1 = base + 8 + r;
    uint4 v0 = make_uint4(0, 0, 0, 0), v1 = make_uint4(0, 0, 0, 0);
    bool g0 = (i0 < end), g1 = (i1 < end);
    int nb0 = g0 ? col[i0] : 0;
    int nb1 = g1 ? col[i1] : 0;
    if (g0) v0 = t8[nb0 * 8 + c];
    if (g1) v1 = t8[nb1 * 8 + c];
    acc[0] += lo16(v0.x) + lo16(v1.x);
    acc[1] += hi16(v0.x) + hi16(v1.x);
    acc[2] += lo16(v0.y) + lo16(v1.y);
    acc[3] += hi16(v0.y) + hi16(v1.y);
    acc[4] += lo16(v0.z) + lo16(v1.z);
    acc[5] += hi16(v0.z) + hi16(v1.z);
    acc[6] += lo16(v0.w) + lo16(v1.w);
    acc[7] += hi16(v0.w) + hi16(v1.w);
  }
#pragma unroll
  for (int m = 8; m <= 32; m <<= 1)
#pragma unroll
    for (int i = 0; i < 8; i++) acc[i] += __shfl_xor(acc[i], m, 64);
}

// ---------- aggregate1: h = relu(mean(t1[nbrs]) + s1) ----------
__global__ __launch_bounds__(256) void aggregate1(const unsigned short* t1,
                                                  const unsigned short* s1,
                                                  const int* row_ptr, const float* invd,
                                                  const int* col, unsigned short* h, int N) {
  int wave = threadIdx.x >> 6, lane = threadIdx.x & 63;
  int r = lane >> 3, c = lane & 7;
  int n = blockIdx.x * 4 + wave;
  if (n >= N) return;
  int start = row_ptr[n], end = row_ptr[n + 1];
  float acc[8] = {0, 0, 0, 0, 0, 0, 0, 0};
  gather_rows((const uint4*)t1, col, start, end, r, c, acc);

  if (r == 0) {
    float id = invd[n];
    uint4 sv = ((const uint4*)s1)[n * 8 + c];
    float s[8] = {lo16(sv.x), hi16(sv.x), lo16(sv.y), hi16(sv.y),
                  lo16(sv.z), hi16(sv.z), lo16(sv.w), hi16(sv.w)};
    unsigned int o[4];
#pragma unroll
    for (int i = 0; i < 4; i++) {
      float a0 = fmaxf(acc[2 * i] * id + s[2 * i], 0.f);
      float a1 = fmaxf(acc[2 * i + 1] * id + s[2 * i + 1], 0.f);
      o[i] = (unsigned int)f2bf(a0) | ((unsigned int)f2bf(a1) << 16);
    }
    ((uint4*)h)[n * 8 + c] = make_uint4(o[0], o[1], o[2], o[3]);
  }
}

// ---------- agg2: aggh = mean(h[nbrs]) ----------
__global__ __launch_bounds__(256) void agg2(const unsigned short* h,
                                            const int* row_ptr, const float* invd,
                                            const int* col, unsigned short* aggh, int N) {
  int wave = threadIdx.x >> 6, lane = threadIdx.x & 63;
  int r = lane >> 3, c = lane & 7;
  int n = blockIdx.x * 4 + wave;
  if (n >= N) return;
  int start = row_ptr[n], end = row_ptr[n + 1];
  float acc[8] = {0, 0, 0, 0, 0, 0, 0, 0};
  gather_rows((const uint4*)h, col, start, end, r, c, acc);

  if (r == 0) {
    float id = invd[n];
    unsigned int o[4];
#pragma unroll
    for (int i = 0; i < 4; i++) {
      o[i] = (unsigned int)f2bf(acc[2 * i] * id) |
             ((unsigned int)f2bf(acc[2 * i + 1] * id) << 16);
    }
    ((uint4*)aggh)[n * 8 + c] = make_uint4(o[0], o[1], o[2], o[3]);
  }
}

// ---------- final: out = log_softmax([aggh|h] @ Wcat + b2) via MFMA ----------
// Per block 64 nodes, 4 waves x 16. K=128 (aggh|h), Nout padded 40->48 (3 nblks).
__global__ __launch_bounds__(256) void final_k(const unsigned short* aggh,
                                               const unsigned short* h,
                                               const unsigned short* Wb2,
                                               const float* b2f,
                                               float* out, int N) {
  int tid = threadIdx.x;
  int lane = tid & 63, wv = tid >> 6;
  int nb = blockIdx.x * 64 + wv * 16;
  int oc = lane & 15, kgrp = lane >> 4;
  int node = min(nb + oc, N - 1);
  f32x4 acc[3];
#pragma unroll
  for (int i = 0; i < 3; i++) acc[i] = (f32x4){0.f, 0.f, 0.f, 0.f};

#pragma unroll
  for (int kb = 0; kb < 4; kb++) {
    int k0 = kb * 32 + kgrp * 8;
    const unsigned short* src = (kb < 2) ? aggh : h;   // k<64 -> aggh, k>=64 -> h
    int kk = k0 & 63;
    bf16x8 af = *(const bf16x8*)&src[(size_t)node * HH + kk];
#pragma unroll
    for (int nblk = 0; nblk < 3; nblk++) {
      bf16x8 bfr = *(const bf16x8*)&Wb2[(nblk * 16 + oc) * 128 + k0];
      acc[nblk] = __builtin_amdgcn_mfma_f32_16x16x32_bf16(af, bfr, acc[nblk], 0, 0, 0);
    }
  }

#pragma unroll
  for (int nblk = 0; nblk < 3; nblk++) {
    int cc = nblk * 16 + oc;
    float bias = (cc < CC) ? b2f[cc] : 0.f;
#pragma unroll
    for (int r = 0; r < 4; r++) acc[nblk][r] += bias;
  }

  // per-node log-softmax: node nn = nb + kgrp*4 + r; its 48 logits live in this
  // lane's 16-lane group (cols 0..15) x 3 nblks at reg r. shfl_xor off<=8 stays in group.
#pragma unroll
  for (int r = 0; r < 4; r++) {
    int nn = nb + kgrp * 4 + r;
    float m = -INFINITY;
#pragma unroll
    for (int nblk = 0; nblk < 3; nblk++)
      if (nblk * 16 + oc < CC) m = fmaxf(m, acc[nblk][r]);
    for (int off = 1; off <= 8; off <<= 1) m = fmaxf(m, __shfl_xor(m, off, 64));
    float s = 0.f;
#pragma unroll
    for (int nblk = 0; nblk < 3; nblk++)
      if (nblk * 16 + oc < CC) s += __expf(acc[nblk][r] - m);
    for (int off = 1; off <= 8; off <<= 1) s += __shfl_xor(s, off, 64);
    float lse = m + __logf(s);
    if (nn < N) {
#pragma unroll
      for (int nblk = 0; nblk < 3; nblk++) {
        int cc = nblk * 16 + oc;
        if (cc < CC) out[(size_t)nn * CC + cc] = acc[nblk][r] - lse;
      }
    }
  }
}

extern "C" void kernel_launch(void* const* d_in, const int* in_sizes, int n_in,
                              void* d_out, int out_size, void* d_ws, size_t ws_size,
                              hipStream_t stream) {
  const void* x   = d_in[0];
  const int*  e   = (const int*)d_in[1];
  const void* W1l = d_in[2];
  const void* W1r = d_in[3];
  const void* b1  = d_in[4];
  const void* W2l = d_in[5];
  const void* W2r = d_in[6];
  const void* b2  = d_in[7];
  float* out = (float*)d_out;

  const int N = in_sizes[0] / DD;            // 100000
  const int E = in_sizes[1] / 2;             // 1600000
  const int nodesPerB = (N + NBUCK - 1) / NBUCK;   // 391
  const int nbuck = (N + nodesPerB - 1) / nodesPerB;
  const int T1B = (N + 63) / 64;             // 1563 (64 nodes per MFMA block)

  char* w = (char*)d_ws;
  size_t off = 0;
  auto carve = [&](size_t bytes) -> void* {
    void* p = (void*)(w + off);
    off += (bytes + 255) & ~(size_t)255;
    return p;
  };
  int* col     = (int*)carve((size_t)E * 4);
  int* row_ptr = (int*)carve((size_t)(N + 1) * 4);
  float* invd  = (float*)carve((size_t)N * 4);
  int* histG   = (int*)carve((size_t)NBUCK * NCHUNK * 4);
  int* ohist   = (int*)carve((size_t)NBUCK * NCHUNK * 4);
  int* bbase   = (int*)carve((NBUCK + 1) * 4);
  int* flags   = (int*)carve(8);
  unsigned short* t1   = (unsigned short*)carve((size_t)N * HH * 2);
  unsigned short* s1   = (unsigned short*)carve((size_t)N * HH * 2);
  unsigned short* h    = (unsigned short*)carve((size_t)N * HH * 2);
  unsigned short* Wb1  = (unsigned short*)carve(128 * 128 * 2);   // [n][k] bf16
  unsigned short* Wb2  = (unsigned short*)carve(48 * 128 * 2);    // [n][k] bf16
  float* b1f   = (float*)carve(HH * sizeof(float));
  float* b2f   = (float*)carve(CC * sizeof(float));
  uint2* ebuf  = (uint2*)carve((size_t)E * 8);
  unsigned short* aggh = (unsigned short*)ebuf;   // alias: ebuf dead after hybrid
  (void)ws_size; (void)n_in; (void)out_size;

  detect<<<1, 256, 0, stream>>>((const unsigned int*)e, (const unsigned int*)x, flags);
  hist_k<<<NCHUNK, 256, 0, stream>>>(e, E, N, flags, nodesPerB, histG);
  hscan_prepw<<<2, 1024, 0, stream>>>(histG, ohist, bbase, row_ptr, N, E,
                                      W1l, W1r, b1, W2l, W2r, b2,
                                      flags, Wb1, Wb2, b1f, b2f);
  scatter_k<<<NCHUNK, 256, 0, stream>>>(e, E, N, flags, nodesPerB, ohist, ebuf);
  bktB_or_t1<<<nbuck + T1B, 256, 0, stream>>>(ebuf, bbase,
                                              nbuck, nodesPerB, row_ptr, invd, col, N,
                                              x, flags, Wb1, b1f, t1, s1, T1B);
  aggregate1<<<(N + 3) / 4, 256, 0, stream>>>(t1, s1, row_ptr, invd, col, h, N);
  agg2<<<(N + 3) / 4, 256, 0, stream>>>(h, row_ptr, invd, col, aggh, N);
  final_k<<<(N + 63) / 64, 256, 0, stream>>>(aggh, h, Wb2, b2f, out, N);
}